// Round 4
// baseline (900.321 us; speedup 1.0000x reference)
//
#include <hip/hip_runtime.h>
#include <math.h>

#define BB 8
#define PP 57744
#define NOBJ 20
#define CC 81
#define ROWS (BB*PP)
#define BPSPLIT 16
#define BPCHUNK ((PP + BPSPLIT - 1) / BPSPLIT)   // 3609
#define KBLK 1280                 // k_conf persistent blocks (5/CU, LDS-capped)
#define NCHUNK (ROWS/64)          // 7218 chunks of 64 rows
#define SELBLK 1024               // co-resident (4096 waves << 8192 capacity)
#define NEGBLK 1024

// ws layout in 4-byte units
// cnt: [0]=num_pos [1]=sl1_sum(f) [2]=pos_ce(f) [3]=neg_ce(f) [4]=neg_cnt
//      [5]=eqCtr [6]=conf_done [7]=skip_flag [8]=prefixA [9]=KrB [10]=T
//      [11]=eqSlots [12]=doneB [13]=negsum_done [14]=flagB [15]=prefixAB
//      [16]=KrC [17]=doneC
#define W_CNT  0
#define W_BP   64                      // 160 u64 (byte 256, 8-aligned)
#define W_HA   1024                    // 16 copies x 2048 bins
#define W_HB   (W_HA + 16*2048)        // 8 copies x 2048
#define W_HC   (W_HB + 8*2048)         // 8 copies x 1024
#define W_CONF (W_HC + 8*1024)         // ROWS ints (byte 233472, 16-aligned)
#define W_KEY  (W_CONF + ROWS)
#define W_CE   (W_KEY + ROWS)
#define MEMSET_BYTES (W_CONF * 4)      // counters + bp + hists

#define SCOPE_AGENT __HIP_MEMORY_SCOPE_AGENT

__device__ __forceinline__ unsigned keymap(float f) {
    unsigned u = __float_as_uint(f);
    return (u & 0x80000000u) ? ~u : (u | 0x80000000u);
}

__device__ __forceinline__ float smooth_l1(float d) {
    float a = fabsf(d);
    return a < 1.f ? 0.5f * d * d : a - 0.5f;
}

__device__ __forceinline__ unsigned aload_u(const unsigned* p) {
    return __hip_atomic_load(p, __ATOMIC_RELAXED, SCOPE_AGENT);
}
__device__ __forceinline__ int aload_i(const int* p) {
    return __hip_atomic_load(p, __ATOMIC_RELAXED, SCOPE_AGENT);
}
__device__ __forceinline__ float aload_f(const float* p) {
    return __hip_atomic_load(p, __ATOMIC_RELAXED, SCOPE_AGENT);
}

// Descending-cumulative threshold search over NB bins summed across NC global
// copies. Finds bin B with suffix(B) >= Kr && suffix(B+1) < Kr; *rem_out =
// Kr - suffix(B+1). Returns -1 if total < Kr. One block, 256 threads.
template <int NB, int NC>
__device__ int scan_bins(const unsigned* h, unsigned Kr, unsigned* rem_out) {
    constexpr int BPT = NB / 256;
    __shared__ unsigned stot[256];
    __shared__ int sbin;
    __shared__ unsigned srem;
    int i = threadIdx.x;
    unsigned v[BPT];
    unsigned tot = 0;
    #pragma unroll
    for (int j = 0; j < BPT; j++) {
        unsigned s = 0;
        #pragma unroll
        for (int c = 0; c < NC; c++) s += aload_u(h + c * NB + i * BPT + j);
        v[j] = s; tot += s;
    }
    if (i == 0) sbin = -1;
    stot[i] = tot; __syncthreads();
    for (int off = 1; off < 256; off <<= 1) {   // inclusive suffix scan
        unsigned add = (i + off < 256) ? stot[i + off] : 0u;
        __syncthreads(); stot[i] += add; __syncthreads();
    }
    unsigned cum = (i < 255) ? stot[i + 1] : 0u;   // suffix of threads > i
    #pragma unroll
    for (int j = BPT - 1; j >= 0; j--) {
        unsigned nxt = cum;      // suffix(bin+1)
        cum += v[j];             // suffix(bin)
        if (cum >= Kr && nxt < Kr) { sbin = i * BPT + j; srem = Kr - nxt; }
    }
    __syncthreads();
    *rem_out = (sbin >= 0) ? srem : 0u;
    return sbin;
}

// Grid (NOBJ, BB, BPSPLIT): per-(gt,batch) argmax over a prior chunk.
__global__ void k_best_prior(const float* __restrict__ priors,
                             const float* __restrict__ gt,
                             unsigned long long* __restrict__ bp) {
    int n = blockIdx.x, b = blockIdx.y;
    int p0 = blockIdx.z * BPCHUNK;
    int p1 = min(p0 + BPCHUNK, PP);
    const float* t = gt + (b * NOBJ + n) * 4;
    float tx1 = t[0], ty1 = t[1], tx2 = t[2], ty2 = t[3];
    float ta = (tx2 - tx1) * (ty2 - ty1);
    unsigned long long best = 0ull;
    for (int p = p0 + threadIdx.x; p < p1; p += 256) {
        float4 pr = ((const float4*)priors)[p];
        float px1 = pr.x - pr.z * 0.5f, py1 = pr.y - pr.w * 0.5f;
        float px2 = pr.x + pr.z * 0.5f, py2 = pr.y + pr.w * 0.5f;
        float iw = fmaxf(fminf(tx2, px2) - fmaxf(tx1, px1), 0.f);
        float ih = fmaxf(fminf(ty2, py2) - fmaxf(ty1, py1), 0.f);
        float inter = iw * ih;
        float iou = inter / (ta + (px2 - px1) * (py2 - py1) - inter);
        unsigned long long pk = ((unsigned long long)__float_as_uint(iou) << 32)
                              | (unsigned long long)(0xFFFFFFFFu - (unsigned)p);
        if (pk > best) best = pk;
    }
    __shared__ unsigned long long sb[256];
    int tid = threadIdx.x;
    sb[tid] = best; __syncthreads();
    for (int s = 128; s > 0; s >>= 1) {
        if (tid < s && sb[tid + s] > sb[tid]) sb[tid] = sb[tid + s];
        __syncthreads();
    }
    if (tid == 0) atomicMax(&bp[b * NOBJ + n], sb[0]);
}

// Per prior: best truth, force-match, conf_t, smooth-L1 for positives.
__global__ void k_match(const float* __restrict__ loc_data,
                        const float* __restrict__ priors,
                        const float* __restrict__ gt,
                        const int* __restrict__ labels,
                        const unsigned long long* __restrict__ bp,
                        int* __restrict__ conf_t,
                        float* __restrict__ cnt_f,
                        int* __restrict__ cnt_i) {
    int b = blockIdx.y;
    int tid = threadIdx.x;
    int p = blockIdx.x * 256 + tid;
    __shared__ float st[NOBJ][4];
    __shared__ int slab[NOBJ], sbp[NOBJ];
    if (tid < NOBJ * 4) ((float*)st)[tid] = gt[b * NOBJ * 4 + tid];
    if (tid < NOBJ) {
        slab[tid] = labels[b * NOBJ + tid];
        sbp[tid] = (int)(0xFFFFFFFFu - (unsigned)bp[b * NOBJ + tid]);
    }
    __syncthreads();
    float s_l1 = 0.f; int is_pos = 0;
    if (p < PP) {
        float4 pr = ((const float4*)priors)[p];
        float px1 = pr.x - pr.z * 0.5f, py1 = pr.y - pr.w * 0.5f;
        float px2 = pr.x + pr.z * 0.5f, py2 = pr.y + pr.w * 0.5f;
        float pa = (px2 - px1) * (py2 - py1);
        float best = -1.f; int bn = 0;
        for (int n = 0; n < NOBJ; n++) {
            float tx1 = st[n][0], ty1 = st[n][1], tx2 = st[n][2], ty2 = st[n][3];
            float iw = fmaxf(fminf(tx2, px2) - fmaxf(tx1, px1), 0.f);
            float ih = fmaxf(fminf(ty2, py2) - fmaxf(ty1, py1), 0.f);
            float inter = iw * ih;
            float iou = inter / ((tx2 - tx1) * (ty2 - ty1) + pa - inter);
            if (iou > best) { best = iou; bn = n; }
        }
        float ov = best;
        for (int n = 0; n < NOBJ; n++)
            if (sbp[n] == p) { bn = n; ov = 2.0f; }
        int conf = slab[bn];
        if (ov < 0.5f) conf = -1;
        if (ov < 0.4f) conf = 0;
        conf_t[b * PP + p] = conf;
        if (conf > 0) {
            is_pos = 1;
            float mx1 = st[bn][0], my1 = st[bn][1], mx2 = st[bn][2], my2 = st[bn][3];
            float gcx = ((mx1 + mx2) * 0.5f - pr.x) / (0.1f * pr.z);
            float gcy = ((my1 + my2) * 0.5f - pr.y) / (0.1f * pr.w);
            float gw = logf((mx2 - mx1) / pr.z) / 0.2f;
            float gh = logf((my2 - my1) / pr.w) / 0.2f;
            float4 ld = ((const float4*)loc_data)[b * PP + p];
            s_l1 = smooth_l1(ld.x - gcx) + smooth_l1(ld.y - gcy) +
                   smooth_l1(ld.z - gw) + smooth_l1(ld.w - gh);
        }
    }
    __shared__ float rs[256]; __shared__ int rc[256];
    rs[tid] = s_l1; rc[tid] = is_pos; __syncthreads();
    for (int s = 128; s > 0; s >>= 1) {
        if (tid < s) { rs[tid] += rs[tid + s]; rc[tid] += rc[tid + s]; }
        __syncthreads();
    }
    if (tid == 0) {
        if (rs[0] != 0.f) atomicAdd(&cnt_f[1], rs[0]);
        if (rc[0])        atomicAdd(&cnt_i[0], rc[0]);
    }
}

// Softmax CE + fg-key per row. Persistent blocks; 64-row chunks staged to LDS
// via fully-coalesced float4 (4 rows == 81 float4 exactly, so a 64-row chunk
// is exactly 1296 float4). Register-prefetch double-buffer: chunk k+1's
// global float4 loads are issued right after the stage barrier and stay in
// flight across the raw end-of-chunk barrier (no vmcnt drain); the only
// latency-absorb point is the counted vmcnt before next chunk's ds_writes.
// Compute: 16 lanes/row register softmax (r1-verified math) from LDS
// (row stride 81 words -> <=2-way banks = free). Pass-A histogram in LDS,
// flushed once per block; last block scans.
__global__ void __launch_bounds__(256, 5)
k_conf(const float* __restrict__ conf_data,
       const int* __restrict__ conf_t,
       unsigned* __restrict__ key,
       float* __restrict__ ce,
       float* __restrict__ cnt_f,
       int* __restrict__ cnt_i,
       unsigned* __restrict__ hA) {
    __shared__ float sx[64 * CC];        // 20736 B
    __shared__ unsigned lhist[2048];     // 8192 B
    __shared__ int sct[64];              // 256 B
    float4* s4 = (float4*)sx;
    const float4* cf4 = (const float4*)conf_data;
    int tid = threadIdx.x;
    int g = tid >> 4, t = tid & 15;
    const float LOG2E = 1.4426950408889634f;

    for (int j = tid; j < 2048; j += 256) lhist[j] = 0;
    __syncthreads();

    float4 p0 = {0,0,0,0}, p1 = p0, p2 = p0, p3 = p0, p4 = p0, p5 = p0;
    int pct = 0;
    int c = blockIdx.x;
    {   // prefetch first chunk
        const float4* base = cf4 + (size_t)c * 1296;
        p0 = base[tid];       p1 = base[tid + 256]; p2 = base[tid + 512];
        p3 = base[tid + 768]; p4 = base[tid + 1024];
        if (tid < 16) p5 = base[1280 + tid];
        if (tid < 64) pct = conf_t[c * 64 + tid];
    }
    for (; c < NCHUNK; c += KBLK) {
        // stage chunk c (compiler inserts counted vmcnt waits before ds_writes)
        s4[tid] = p0; s4[tid + 256] = p1; s4[tid + 512] = p2;
        s4[tid + 768] = p3; s4[tid + 1024] = p4;
        if (tid < 16) s4[1280 + tid] = p5;
        if (tid < 64) sct[tid] = pct;
        __syncthreads();   // full drain harmless: nothing else outstanding here

        int cn = c + KBLK;
        if (cn < NCHUNK) {   // issue next chunk's loads; they fly across compute
            const float4* base = cf4 + (size_t)cn * 1296;
            p0 = base[tid];       p1 = base[tid + 256]; p2 = base[tid + 512];
            p3 = base[tid + 768]; p4 = base[tid + 1024];
            if (tid < 16) p5 = base[1280 + tid];
            if (tid < 64) pct = conf_t[cn * 64 + tid];
        }

        // compute 4 rows per 16-lane group (wave handles consecutive rows)
        #pragma unroll
        for (int i = 0; i < 4; i++) {
            int rloc = i * 16 + g;
            int row = c * 64 + rloc;
            const float* x = sx + rloc * CC;
            float a0 = x[t], a1 = x[t + 16], a2 = x[t + 32],
                  a3 = x[t + 48], a4 = x[t + 64];
            float a5 = -INFINITY; if (t == 0) a5 = x[80];
            int cct = sct[rloc];

            float fg = fmaxf(fmaxf(fmaxf(a1, a2), fmaxf(a3, a4)), a5);
            if (t != 0) fg = fmaxf(fg, a0);
            fg = fmaxf(fg, __shfl_xor(fg, 1));
            fg = fmaxf(fg, __shfl_xor(fg, 2));
            fg = fmaxf(fg, __shfl_xor(fg, 4));
            fg = fmaxf(fg, __shfl_xor(fg, 8));
            float x0 = __shfl(a0, tid & 48);
            float m = fmaxf(fg, x0);
            float e = exp2f((a0 - m) * LOG2E) + exp2f((a1 - m) * LOG2E)
                    + exp2f((a2 - m) * LOG2E) + exp2f((a3 - m) * LOG2E)
                    + exp2f((a4 - m) * LOG2E) + exp2f((a5 - m) * LOG2E);
            e += __shfl_xor(e, 1);
            e += __shfl_xor(e, 2);
            e += __shfl_xor(e, 4);
            e += __shfl_xor(e, 8);
            int ctc = min(max(cct, 0), CC - 1);
            int kk = ctc >> 4;
            float sel = (kk == 0) ? a0 : (kk == 1) ? a1 : (kk == 2) ? a2
                      : (kk == 3) ? a3 : (kk == 4) ? a4 : a5;
            float xc = __shfl(sel, (tid & 48) | (ctc & 15));
            if (t == 0) {
                float lse = m + log2f(e) * 0.6931471805599453f;
                float cev = lse - xc;
                ce[row] = cev;
                unsigned kv = (cct == 0) ? keymap(fg) : 0u;
                key[row] = kv;
                if (cct > 0) atomicAdd(&cnt_f[2], cev);
                if (cct == 0) atomicAdd(&lhist[kv >> 21], 1u);
            }
        }
        // raw barrier: done reading sx before next overwrite; prefetch loads
        // stay in flight (no vmcnt drain here).
        __builtin_amdgcn_sched_barrier(0);
        __builtin_amdgcn_s_barrier();
        __builtin_amdgcn_sched_barrier(0);
    }

    // flush LDS hist to one of 16 global copies
    __syncthreads();
    unsigned* hmy = hA + (blockIdx.x & 15) * 2048;
    for (int j = tid; j < 2048; j += 256)
        if (lhist[j]) atomicAdd(&hmy[j], lhist[j]);

    __threadfence();
    __shared__ int amLast;
    if (tid == 0)
        amLast = (__hip_atomic_fetch_add((unsigned*)&cnt_i[6], 1u,
                   __ATOMIC_ACQ_REL, SCOPE_AGENT) == (unsigned)(gridDim.x - 1));
    __syncthreads();
    if (!amLast) return;

    unsigned Kr = 3u * (unsigned)cnt_i[0];
    if (Kr == 0) {   // no positives: select no negatives
        if (tid == 0) { cnt_i[7] = 1; cnt_i[10] = (int)0xFFFFFFFFu; cnt_i[11] = 0; }
        return;
    }
    unsigned rem; int bin = scan_bins<2048, 16>(hA, Kr, &rem);
    if (tid == 0) {
        if (bin < 0) { cnt_i[7] = 1; cnt_i[10] = 0; cnt_i[11] = 0; }  // select all
        else         { cnt_i[8] = bin; cnt_i[9] = (int)rem; }
    }
}

// Passes B (bits 20:10) and C (bits 9:0) in one kernel: LDS-private hists,
// 8 global copies, done-counter + release/acquire spin between passes.
// SELBLK=1024 blocks are guaranteed co-resident (4-wave, 8KB-LDS blocks:
// capacity >= 2048 blocks), so the spin cannot deadlock.
__global__ void __launch_bounds__(256) k_sel(const unsigned* __restrict__ key,
                                             int* __restrict__ cnt_i,
                                             unsigned* __restrict__ hB,
                                             unsigned* __restrict__ hC) {
    if (cnt_i[7]) return;   // threshold already fully decided in pass A
    __shared__ unsigned lh[2048];
    __shared__ int amLast;
    int tid = threadIdx.x;
    unsigned prefixA = (unsigned)cnt_i[8];
    unsigned KrB = (unsigned)cnt_i[9];
    const uint4* k4 = (const uint4*)key;
    int n4 = ROWS / 4;

    // ---- pass B ----
    for (int j = tid; j < 2048; j += 256) lh[j] = 0;
    __syncthreads();
    for (int r = blockIdx.x * 256 + tid; r < n4; r += gridDim.x * 256) {
        uint4 k = k4[r];
        if (k.x && (k.x >> 21) == prefixA) atomicAdd(&lh[(k.x >> 10) & 0x7FFu], 1u);
        if (k.y && (k.y >> 21) == prefixA) atomicAdd(&lh[(k.y >> 10) & 0x7FFu], 1u);
        if (k.z && (k.z >> 21) == prefixA) atomicAdd(&lh[(k.z >> 10) & 0x7FFu], 1u);
        if (k.w && (k.w >> 21) == prefixA) atomicAdd(&lh[(k.w >> 10) & 0x7FFu], 1u);
    }
    __syncthreads();
    {
        unsigned* hmy = hB + (blockIdx.x & 7) * 2048;
        for (int j = tid; j < 2048; j += 256)
            if (lh[j]) atomicAdd(&hmy[j], lh[j]);
    }
    __threadfence();
    if (tid == 0)
        amLast = (__hip_atomic_fetch_add((unsigned*)&cnt_i[12], 1u,
                   __ATOMIC_ACQ_REL, SCOPE_AGENT) == (unsigned)(gridDim.x - 1));
    __syncthreads();
    if (amLast) {
        unsigned rem; int bin = scan_bins<2048, 8>(hB, KrB, &rem);
        if (bin < 0) { bin = 0; rem = 0; }   // defensive (cannot happen)
        if (tid == 0) {
            __hip_atomic_store(&cnt_i[15], (int)((prefixA << 11) | (unsigned)bin),
                               __ATOMIC_RELAXED, SCOPE_AGENT);
            __hip_atomic_store(&cnt_i[16], (int)rem, __ATOMIC_RELAXED, SCOPE_AGENT);
            __hip_atomic_store(&cnt_i[14], 1, __ATOMIC_RELEASE, SCOPE_AGENT);
        }
    }
    // spin until pass-B threshold published
    if (tid == 0) {
        while (__hip_atomic_load(&cnt_i[14], __ATOMIC_ACQUIRE, SCOPE_AGENT) == 0)
            __builtin_amdgcn_s_sleep(16);
    }
    __syncthreads();
    unsigned prefixAB = (unsigned)aload_i(&cnt_i[15]);
    unsigned KrC = (unsigned)aload_i(&cnt_i[16]);

    // ---- pass C ----
    for (int j = tid; j < 1024; j += 256) lh[j] = 0;
    __syncthreads();
    for (int r = blockIdx.x * 256 + tid; r < n4; r += gridDim.x * 256) {
        uint4 k = k4[r];
        if (k.x && (k.x >> 10) == prefixAB) atomicAdd(&lh[k.x & 0x3FFu], 1u);
        if (k.y && (k.y >> 10) == prefixAB) atomicAdd(&lh[k.y & 0x3FFu], 1u);
        if (k.z && (k.z >> 10) == prefixAB) atomicAdd(&lh[k.z & 0x3FFu], 1u);
        if (k.w && (k.w >> 10) == prefixAB) atomicAdd(&lh[k.w & 0x3FFu], 1u);
    }
    __syncthreads();
    {
        unsigned* hmy = hC + (blockIdx.x & 7) * 1024;
        for (int j = tid; j < 1024; j += 256)
            if (lh[j]) atomicAdd(&hmy[j], lh[j]);
    }
    __threadfence();
    if (tid == 0)
        amLast = (__hip_atomic_fetch_add((unsigned*)&cnt_i[17], 1u,
                   __ATOMIC_ACQ_REL, SCOPE_AGENT) == (unsigned)(gridDim.x - 1));
    __syncthreads();
    if (!amLast) return;
    unsigned rem; int bin = scan_bins<1024, 8>(hC, KrC, &rem);
    if (bin < 0) { bin = 0; rem = 0; }       // defensive
    if (tid == 0) {
        cnt_i[10] = (int)((prefixAB << 10) | (unsigned)bin);
        cnt_i[11] = (int)rem;
    }
}

// Sum CE over selected negatives (key > T, or == T up to eqSlots); last block
// computes the final two losses.
__global__ void __launch_bounds__(256) k_negsum(const unsigned* __restrict__ key,
                                                const float* __restrict__ ce,
                                                const int* __restrict__ conf_t,
                                                int* __restrict__ cnt_i,
                                                float* __restrict__ cnt_f,
                                                float* __restrict__ out) {
    int tid = threadIdx.x;
    unsigned T = (unsigned)cnt_i[10];
    int eqS = cnt_i[11];
    float s = 0.f; int c = 0;
    const uint4* k4 = (const uint4*)key;
    const int4* ct4 = (const int4*)conf_t;
    int n4 = ROWS / 4;
    for (int r = blockIdx.x * 256 + tid; r < n4; r += gridDim.x * 256) {
        uint4 k = k4[r]; int4 ctv = ct4[r];
        #define DO_ONE(comp, idx) { \
            if (ctv.comp == 0) { \
                unsigned kk = k.comp; bool selr = false; \
                if (kk > T) selr = true; \
                else if (kk == T) { int slot = atomicAdd(&cnt_i[5], 1); selr = slot < eqS; } \
                if (selr) { s += ce[4 * r + idx]; c++; } \
            } }
        DO_ONE(x, 0) DO_ONE(y, 1) DO_ONE(z, 2) DO_ONE(w, 3)
        #undef DO_ONE
    }
    __shared__ float rs[256]; __shared__ int rc[256];
    rs[tid] = s; rc[tid] = c; __syncthreads();
    for (int st = 128; st > 0; st >>= 1) {
        if (tid < st) { rs[tid] += rs[tid + st]; rc[tid] += rc[tid + st]; }
        __syncthreads();
    }
    if (tid == 0) {
        if (rs[0] != 0.f) atomicAdd(&cnt_f[3], rs[0]);
        if (rc[0])        atomicAdd(&cnt_i[4], rc[0]);
    }
    __threadfence();
    __syncthreads();
    if (tid == 0 &&
        __hip_atomic_fetch_add((unsigned*)&cnt_i[13], 1u,
            __ATOMIC_ACQ_REL, SCOPE_AGENT) == (unsigned)(gridDim.x - 1)) {
        int np = aload_i(&cnt_i[0]);
        int nn = aload_i(&cnt_i[4]);
        float f1 = aload_f(&cnt_f[1]);
        float f2 = aload_f(&cnt_f[2]);
        float f3 = aload_f(&cnt_f[3]);
        out[0] = f1 / (float)max(np, 1);
        out[1] = (f2 + f3) / (float)max(np + nn, 1);
    }
}

extern "C" void kernel_launch(void* const* d_in, const int* in_sizes, int n_in,
                              void* d_out, int out_size, void* d_ws, size_t ws_size,
                              hipStream_t stream) {
    const float* loc    = (const float*)d_in[0];
    const float* conf   = (const float*)d_in[1];
    const float* priors = (const float*)d_in[2];
    const float* gt     = (const float*)d_in[3];
    const int*   labels = (const int*)d_in[4];
    float* out = (float*)d_out;
    int*      wi = (int*)d_ws;
    float*    wf = (float*)d_ws;
    unsigned* wu = (unsigned*)d_ws;
    unsigned long long* wbp = (unsigned long long*)(wi + W_BP);

    hipMemsetAsync(d_ws, 0, MEMSET_BYTES, stream);  // counters + bp + hists
    k_best_prior<<<dim3(NOBJ, BB, BPSPLIT), 256, 0, stream>>>(priors, gt, wbp);
    k_match<<<dim3((PP + 255) / 256, BB), 256, 0, stream>>>(
        loc, priors, gt, labels, wbp, wi + W_CONF, wf, wi);
    k_conf<<<KBLK, 256, 0, stream>>>(conf, wi + W_CONF, wu + W_KEY, wf + W_CE,
                                     wf, wi, wu + W_HA);
    k_sel<<<SELBLK, 256, 0, stream>>>(wu + W_KEY, wi, wu + W_HB, wu + W_HC);
    k_negsum<<<NEGBLK, 256, 0, stream>>>(wu + W_KEY, wf + W_CE, wi + W_CONF,
                                         wi, wf, out);
}

// Round 5
// 814.310 us; speedup vs baseline: 1.1056x; 1.1056x over previous
//
#include <hip/hip_runtime.h>
#include <math.h>

#define BB 8
#define PP 57744
#define NOBJ 20
#define CC 81
#define ROWS (BB*PP)
#define RPB 64        // rows per block in k_conf (round-0 proven structure)
#define BPSPLIT 16
#define BPCHUNK ((PP + BPSPLIT - 1) / BPSPLIT)   // 3609
#define SELBLK 1024   // k_sel blocks — co-resident (4-wave, 8KB-LDS: cap 2048)
#define NEGBLK 512

// ws layout in 4-byte units
// cnt: [0]=num_pos [1]=sl1_sum(f) [2]=pos_ce(f) [3]=neg_ce(f) [4]=neg_cnt
//      [5]=eqCtr [6]=doneA [7]=skip [8]=prefixA [9]=KrB [10]=T [11]=eqSlots
//      [12]=doneB [13]=negsum_done [14]=flagB [15]=prefixAB [16]=KrC
//      [17]=doneC [20]=flagA
#define W_CNT  0
#define W_BP   64                      // 160 u64 (byte 256, 8-aligned)
#define W_HA   1024                    // 8 copies x 2048 bins
#define W_HB   (W_HA + 8*2048)
#define W_HC   (W_HB + 8*2048)         // 8 copies x 1024
#define W_CONF (W_HC + 8*1024)         // ROWS ints
#define W_KEY  (W_CONF + ROWS)
#define W_CE   (W_KEY + ROWS)
#define MEMSET_BYTES (W_CONF * 4)      // counters + bp + hists

#define SCOPE_AGENT __HIP_MEMORY_SCOPE_AGENT

__device__ __forceinline__ unsigned keymap(float f) {
    unsigned u = __float_as_uint(f);
    return (u & 0x80000000u) ? ~u : (u | 0x80000000u);
}

__device__ __forceinline__ float smooth_l1(float d) {
    float a = fabsf(d);
    return a < 1.f ? 0.5f * d * d : a - 0.5f;
}

__device__ __forceinline__ unsigned aload_u(const unsigned* p) {
    return __hip_atomic_load(p, __ATOMIC_RELAXED, SCOPE_AGENT);
}
__device__ __forceinline__ int aload_i(const int* p) {
    return __hip_atomic_load(p, __ATOMIC_RELAXED, SCOPE_AGENT);
}
__device__ __forceinline__ float aload_f(const float* p) {
    return __hip_atomic_load(p, __ATOMIC_RELAXED, SCOPE_AGENT);
}

// Descending-cumulative threshold search over NB bins summed across NC global
// copies. Finds bin B with suffix(B) >= Kr && suffix(B+1) < Kr; *rem_out =
// Kr - suffix(B+1). Returns -1 if total < Kr. One block, 256 threads.
template <int NB, int NC>
__device__ int scan_bins(const unsigned* h, unsigned Kr, unsigned* rem_out) {
    constexpr int BPT = NB / 256;
    __shared__ unsigned stot[256];
    __shared__ int sbin;
    __shared__ unsigned srem;
    int i = threadIdx.x;
    unsigned v[BPT];
    unsigned tot = 0;
    #pragma unroll
    for (int j = 0; j < BPT; j++) {
        unsigned s = 0;
        #pragma unroll
        for (int c = 0; c < NC; c++) s += aload_u(h + c * NB + i * BPT + j);
        v[j] = s; tot += s;
    }
    if (i == 0) sbin = -1;
    stot[i] = tot; __syncthreads();
    for (int off = 1; off < 256; off <<= 1) {   // inclusive suffix scan
        unsigned add = (i + off < 256) ? stot[i + off] : 0u;
        __syncthreads(); stot[i] += add; __syncthreads();
    }
    unsigned cum = (i < 255) ? stot[i + 1] : 0u;   // suffix of threads > i
    #pragma unroll
    for (int j = BPT - 1; j >= 0; j--) {
        unsigned nxt = cum;      // suffix(bin+1)
        cum += v[j];             // suffix(bin)
        if (cum >= Kr && nxt < Kr) { sbin = i * BPT + j; srem = Kr - nxt; }
    }
    __syncthreads();
    *rem_out = (sbin >= 0) ? srem : 0u;
    return sbin;
}

// Grid (NOBJ, BB, BPSPLIT): per-(gt,batch) argmax over a prior chunk.
__global__ void k_best_prior(const float* __restrict__ priors,
                             const float* __restrict__ gt,
                             unsigned long long* __restrict__ bp) {
    int n = blockIdx.x, b = blockIdx.y;
    int p0 = blockIdx.z * BPCHUNK;
    int p1 = min(p0 + BPCHUNK, PP);
    const float* t = gt + (b * NOBJ + n) * 4;
    float tx1 = t[0], ty1 = t[1], tx2 = t[2], ty2 = t[3];
    float ta = (tx2 - tx1) * (ty2 - ty1);
    unsigned long long best = 0ull;
    for (int p = p0 + threadIdx.x; p < p1; p += 256) {
        float4 pr = ((const float4*)priors)[p];
        float px1 = pr.x - pr.z * 0.5f, py1 = pr.y - pr.w * 0.5f;
        float px2 = pr.x + pr.z * 0.5f, py2 = pr.y + pr.w * 0.5f;
        float iw = fmaxf(fminf(tx2, px2) - fmaxf(tx1, px1), 0.f);
        float ih = fmaxf(fminf(ty2, py2) - fmaxf(ty1, py1), 0.f);
        float inter = iw * ih;
        float iou = inter / (ta + (px2 - px1) * (py2 - py1) - inter);
        unsigned long long pk = ((unsigned long long)__float_as_uint(iou) << 32)
                              | (unsigned long long)(0xFFFFFFFFu - (unsigned)p);
        if (pk > best) best = pk;
    }
    __shared__ unsigned long long sb[256];
    int tid = threadIdx.x;
    sb[tid] = best; __syncthreads();
    for (int s = 128; s > 0; s >>= 1) {
        if (tid < s && sb[tid + s] > sb[tid]) sb[tid] = sb[tid + s];
        __syncthreads();
    }
    if (tid == 0) atomicMax(&bp[b * NOBJ + n], sb[0]);
}

// Per prior: best truth, force-match, conf_t, smooth-L1 for positives.
__global__ void k_match(const float* __restrict__ loc_data,
                        const float* __restrict__ priors,
                        const float* __restrict__ gt,
                        const int* __restrict__ labels,
                        const unsigned long long* __restrict__ bp,
                        int* __restrict__ conf_t,
                        float* __restrict__ cnt_f,
                        int* __restrict__ cnt_i) {
    int b = blockIdx.y;
    int tid = threadIdx.x;
    int p = blockIdx.x * 256 + tid;
    __shared__ float st[NOBJ][4];
    __shared__ int slab[NOBJ], sbp[NOBJ];
    if (tid < NOBJ * 4) ((float*)st)[tid] = gt[b * NOBJ * 4 + tid];
    if (tid < NOBJ) {
        slab[tid] = labels[b * NOBJ + tid];
        sbp[tid] = (int)(0xFFFFFFFFu - (unsigned)bp[b * NOBJ + tid]);
    }
    __syncthreads();
    float s_l1 = 0.f; int is_pos = 0;
    if (p < PP) {
        float4 pr = ((const float4*)priors)[p];
        float px1 = pr.x - pr.z * 0.5f, py1 = pr.y - pr.w * 0.5f;
        float px2 = pr.x + pr.z * 0.5f, py2 = pr.y + pr.w * 0.5f;
        float pa = (px2 - px1) * (py2 - py1);
        float best = -1.f; int bn = 0;
        for (int n = 0; n < NOBJ; n++) {
            float tx1 = st[n][0], ty1 = st[n][1], tx2 = st[n][2], ty2 = st[n][3];
            float iw = fmaxf(fminf(tx2, px2) - fmaxf(tx1, px1), 0.f);
            float ih = fmaxf(fminf(ty2, py2) - fmaxf(ty1, py1), 0.f);
            float inter = iw * ih;
            float iou = inter / ((tx2 - tx1) * (ty2 - ty1) + pa - inter);
            if (iou > best) { best = iou; bn = n; }
        }
        float ov = best;
        for (int n = 0; n < NOBJ; n++)
            if (sbp[n] == p) { bn = n; ov = 2.0f; }
        int conf = slab[bn];
        if (ov < 0.5f) conf = -1;
        if (ov < 0.4f) conf = 0;
        conf_t[b * PP + p] = conf;
        if (conf > 0) {
            is_pos = 1;
            float mx1 = st[bn][0], my1 = st[bn][1], mx2 = st[bn][2], my2 = st[bn][3];
            float gcx = ((mx1 + mx2) * 0.5f - pr.x) / (0.1f * pr.z);
            float gcy = ((my1 + my2) * 0.5f - pr.y) / (0.1f * pr.w);
            float gw = logf((mx2 - mx1) / pr.z) / 0.2f;
            float gh = logf((my2 - my1) / pr.w) / 0.2f;
            float4 ld = ((const float4*)loc_data)[b * PP + p];
            s_l1 = smooth_l1(ld.x - gcx) + smooth_l1(ld.y - gcy) +
                   smooth_l1(ld.z - gw) + smooth_l1(ld.w - gh);
        }
    }
    __shared__ float rs[256]; __shared__ int rc[256];
    rs[tid] = s_l1; rc[tid] = is_pos; __syncthreads();
    for (int s = 128; s > 0; s >>= 1) {
        if (tid < s) { rs[tid] += rs[tid + s]; rc[tid] += rc[tid + s]; }
        __syncthreads();
    }
    if (tid == 0) {
        if (rs[0] != 0.f) atomicAdd(&cnt_f[1], rs[0]);
        if (rc[0])        atomicAdd(&cnt_i[0], rc[0]);
    }
}

// Round-0 proven structure: 64 rows per one-shot block staged via coalesced
// float4 -> LDS; 4 threads/row serial scan with native exp2/log2.
// 7218 blocks * 5184 floats == ROWS*81 exactly.
__global__ void __launch_bounds__(256) k_conf(const float* __restrict__ conf_data,
                                              const int* __restrict__ conf_t,
                                              unsigned* __restrict__ key,
                                              float* __restrict__ ce,
                                              float* __restrict__ cnt_f) {
    __shared__ float sx[RPB * CC];   // 20736 B
    int tid = threadIdx.x;
    const float4* g = (const float4*)(conf_data + (size_t)blockIdx.x * (RPB * CC));
    float4* s4 = (float4*)sx;
    #pragma unroll
    for (int i = 0; i < 5; i++) s4[tid + 256 * i] = g[tid + 256 * i];
    if (tid < (RPB * CC / 4) - 1280) s4[1280 + tid] = g[1280 + tid];
    __syncthreads();

    int r = tid >> 2, t = tid & 3;
    int row = blockIdx.x * RPB + r;
    const float* x = sx + r * CC;

    float m = (t == 0) ? x[0] : -INFINITY;
    float fg = -INFINITY;
    for (int c = (t == 0) ? 4 : t; c < CC; c += 4) {
        float v = x[c];
        m = fmaxf(m, v);
        fg = fmaxf(fg, v);
    }
    m = fmaxf(m, __shfl_xor(m, 1));
    m = fmaxf(m, __shfl_xor(m, 2));
    fg = fmaxf(fg, __shfl_xor(fg, 1));
    fg = fmaxf(fg, __shfl_xor(fg, 2));

    const float LOG2E = 1.4426950408889634f;
    float e = 0.f;
    for (int c = t; c < CC; c += 4) e += exp2f((x[c] - m) * LOG2E);
    e += __shfl_xor(e, 1);
    e += __shfl_xor(e, 2);

    if (t == 0) {
        float lse = m + log2f(e) * 0.6931471805599453f;
        int ct = conf_t[row];
        int ctc = min(max(ct, 0), CC - 1);
        float cev = lse - x[ctc];
        ce[row] = cev;
        key[row] = (ct == 0) ? keymap(fg) : 0u;
        if (ct > 0) atomicAdd(&cnt_f[2], cev);
    }
}

// All three radix-select phases (bits 31:21, 20:10, 9:0) in ONE kernel.
// Per phase: LDS-private hist over grid-stride key pass, flush to 8 spread
// global copies, done-counter; last block scans and publishes with a
// release flag; all blocks spin (s_sleep) on the flag. SELBLK=1024 blocks
// are guaranteed co-resident (4-wave / 8KB-LDS blocks -> capacity 2048),
// so the spins cannot deadlock. Pattern proven correct in rounds 3 & 4.
__global__ void __launch_bounds__(256) k_sel(const unsigned* __restrict__ key,
                                             int* __restrict__ cnt_i,
                                             unsigned* __restrict__ hA,
                                             unsigned* __restrict__ hB,
                                             unsigned* __restrict__ hC) {
    __shared__ unsigned lh[2048];
    __shared__ int amLast;
    int tid = threadIdx.x;
    const uint4* k4 = (const uint4*)key;
    int n4 = ROWS / 4;

    // ---- phase A: bits 31:21 ----
    for (int j = tid; j < 2048; j += 256) lh[j] = 0;
    __syncthreads();
    for (int r = blockIdx.x * 256 + tid; r < n4; r += gridDim.x * 256) {
        uint4 k = k4[r];
        if (k.x) atomicAdd(&lh[k.x >> 21], 1u);
        if (k.y) atomicAdd(&lh[k.y >> 21], 1u);
        if (k.z) atomicAdd(&lh[k.z >> 21], 1u);
        if (k.w) atomicAdd(&lh[k.w >> 21], 1u);
    }
    __syncthreads();
    {
        unsigned* hmy = hA + (blockIdx.x & 7) * 2048;
        for (int j = tid; j < 2048; j += 256)
            if (lh[j]) atomicAdd(&hmy[j], lh[j]);
    }
    __threadfence();
    if (tid == 0)
        amLast = (__hip_atomic_fetch_add((unsigned*)&cnt_i[6], 1u,
                   __ATOMIC_ACQ_REL, SCOPE_AGENT) == (unsigned)(gridDim.x - 1));
    __syncthreads();
    if (amLast) {
        unsigned Kr = 3u * (unsigned)cnt_i[0];
        if (Kr == 0) {           // no positives: select no negatives
            if (tid == 0) {
                cnt_i[10] = (int)0xFFFFFFFFu; cnt_i[11] = 0;
                __hip_atomic_store(&cnt_i[7], 1, __ATOMIC_RELAXED, SCOPE_AGENT);
            }
        } else {
            unsigned rem; int bin = scan_bins<2048, 8>(hA, Kr, &rem);
            if (tid == 0) {
                if (bin < 0) {   // total < Kr: select all candidates
                    cnt_i[10] = 0; cnt_i[11] = 0;
                    __hip_atomic_store(&cnt_i[7], 1, __ATOMIC_RELAXED, SCOPE_AGENT);
                } else {
                    __hip_atomic_store(&cnt_i[8], bin, __ATOMIC_RELAXED, SCOPE_AGENT);
                    __hip_atomic_store(&cnt_i[9], (int)rem, __ATOMIC_RELAXED, SCOPE_AGENT);
                }
            }
        }
        if (tid == 0)
            __hip_atomic_store(&cnt_i[20], 1, __ATOMIC_RELEASE, SCOPE_AGENT);
    }
    if (tid == 0) {
        while (__hip_atomic_load(&cnt_i[20], __ATOMIC_ACQUIRE, SCOPE_AGENT) == 0)
            __builtin_amdgcn_s_sleep(16);
    }
    __syncthreads();
    if (aload_i(&cnt_i[7])) return;
    unsigned prefixA = (unsigned)aload_i(&cnt_i[8]);
    unsigned KrB = (unsigned)aload_i(&cnt_i[9]);

    // ---- phase B: bits 20:10 within prefixA ----
    for (int j = tid; j < 2048; j += 256) lh[j] = 0;
    __syncthreads();
    for (int r = blockIdx.x * 256 + tid; r < n4; r += gridDim.x * 256) {
        uint4 k = k4[r];
        if (k.x && (k.x >> 21) == prefixA) atomicAdd(&lh[(k.x >> 10) & 0x7FFu], 1u);
        if (k.y && (k.y >> 21) == prefixA) atomicAdd(&lh[(k.y >> 10) & 0x7FFu], 1u);
        if (k.z && (k.z >> 21) == prefixA) atomicAdd(&lh[(k.z >> 10) & 0x7FFu], 1u);
        if (k.w && (k.w >> 21) == prefixA) atomicAdd(&lh[(k.w >> 10) & 0x7FFu], 1u);
    }
    __syncthreads();
    {
        unsigned* hmy = hB + (blockIdx.x & 7) * 2048;
        for (int j = tid; j < 2048; j += 256)
            if (lh[j]) atomicAdd(&hmy[j], lh[j]);
    }
    __threadfence();
    if (tid == 0)
        amLast = (__hip_atomic_fetch_add((unsigned*)&cnt_i[12], 1u,
                   __ATOMIC_ACQ_REL, SCOPE_AGENT) == (unsigned)(gridDim.x - 1));
    __syncthreads();
    if (amLast) {
        unsigned rem; int bin = scan_bins<2048, 8>(hB, KrB, &rem);
        if (bin < 0) { bin = 0; rem = 0; }   // defensive (cannot happen)
        if (tid == 0) {
            __hip_atomic_store(&cnt_i[15], (int)((prefixA << 11) | (unsigned)bin),
                               __ATOMIC_RELAXED, SCOPE_AGENT);
            __hip_atomic_store(&cnt_i[16], (int)rem, __ATOMIC_RELAXED, SCOPE_AGENT);
            __hip_atomic_store(&cnt_i[14], 1, __ATOMIC_RELEASE, SCOPE_AGENT);
        }
    }
    if (tid == 0) {
        while (__hip_atomic_load(&cnt_i[14], __ATOMIC_ACQUIRE, SCOPE_AGENT) == 0)
            __builtin_amdgcn_s_sleep(16);
    }
    __syncthreads();
    unsigned prefixAB = (unsigned)aload_i(&cnt_i[15]);
    unsigned KrC = (unsigned)aload_i(&cnt_i[16]);

    // ---- phase C: bits 9:0 within prefixAB ----
    for (int j = tid; j < 1024; j += 256) lh[j] = 0;
    __syncthreads();
    for (int r = blockIdx.x * 256 + tid; r < n4; r += gridDim.x * 256) {
        uint4 k = k4[r];
        if (k.x && (k.x >> 10) == prefixAB) atomicAdd(&lh[k.x & 0x3FFu], 1u);
        if (k.y && (k.y >> 10) == prefixAB) atomicAdd(&lh[k.y & 0x3FFu], 1u);
        if (k.z && (k.z >> 10) == prefixAB) atomicAdd(&lh[k.z & 0x3FFu], 1u);
        if (k.w && (k.w >> 10) == prefixAB) atomicAdd(&lh[k.w & 0x3FFu], 1u);
    }
    __syncthreads();
    {
        unsigned* hmy = hC + (blockIdx.x & 7) * 1024;
        for (int j = tid; j < 1024; j += 256)
            if (lh[j]) atomicAdd(&hmy[j], lh[j]);
    }
    __threadfence();
    if (tid == 0)
        amLast = (__hip_atomic_fetch_add((unsigned*)&cnt_i[17], 1u,
                   __ATOMIC_ACQ_REL, SCOPE_AGENT) == (unsigned)(gridDim.x - 1));
    __syncthreads();
    if (!amLast) return;
    unsigned rem; int bin = scan_bins<1024, 8>(hC, KrC, &rem);
    if (bin < 0) { bin = 0; rem = 0; }       // defensive
    if (tid == 0) {
        cnt_i[10] = (int)((prefixAB << 10) | (unsigned)bin);
        cnt_i[11] = (int)rem;
    }
}

// Sum CE over selected negatives (key > T, or == T up to eqSlots); last block
// computes the final two losses.
__global__ void __launch_bounds__(256) k_negsum(const unsigned* __restrict__ key,
                                                const float* __restrict__ ce,
                                                const int* __restrict__ conf_t,
                                                int* __restrict__ cnt_i,
                                                float* __restrict__ cnt_f,
                                                float* __restrict__ out) {
    int tid = threadIdx.x;
    unsigned T = (unsigned)cnt_i[10];
    int eqS = cnt_i[11];
    float s = 0.f; int c = 0;
    const uint4* k4 = (const uint4*)key;
    const int4* ct4 = (const int4*)conf_t;
    int n4 = ROWS / 4;
    for (int r = blockIdx.x * 256 + tid; r < n4; r += gridDim.x * 256) {
        uint4 k = k4[r]; int4 ctv = ct4[r];
        #define DO_ONE(comp, idx) { \
            if (ctv.comp == 0) { \
                unsigned kk = k.comp; bool selr = false; \
                if (kk > T) selr = true; \
                else if (kk == T) { int slot = atomicAdd(&cnt_i[5], 1); selr = slot < eqS; } \
                if (selr) { s += ce[4 * r + idx]; c++; } \
            } }
        DO_ONE(x, 0) DO_ONE(y, 1) DO_ONE(z, 2) DO_ONE(w, 3)
        #undef DO_ONE
    }
    __shared__ float rs[256]; __shared__ int rc[256];
    rs[tid] = s; rc[tid] = c; __syncthreads();
    for (int st = 128; st > 0; st >>= 1) {
        if (tid < st) { rs[tid] += rs[tid + st]; rc[tid] += rc[tid + st]; }
        __syncthreads();
    }
    if (tid == 0) {
        if (rs[0] != 0.f) atomicAdd(&cnt_f[3], rs[0]);
        if (rc[0])        atomicAdd(&cnt_i[4], rc[0]);
    }
    __threadfence();
    __syncthreads();
    if (tid == 0 &&
        __hip_atomic_fetch_add((unsigned*)&cnt_i[13], 1u,
            __ATOMIC_ACQ_REL, SCOPE_AGENT) == (unsigned)(gridDim.x - 1)) {
        int np = aload_i(&cnt_i[0]);
        int nn = aload_i(&cnt_i[4]);
        float f1 = aload_f(&cnt_f[1]);
        float f2 = aload_f(&cnt_f[2]);
        float f3 = aload_f(&cnt_f[3]);
        out[0] = f1 / (float)max(np, 1);
        out[1] = (f2 + f3) / (float)max(np + nn, 1);
    }
}

extern "C" void kernel_launch(void* const* d_in, const int* in_sizes, int n_in,
                              void* d_out, int out_size, void* d_ws, size_t ws_size,
                              hipStream_t stream) {
    const float* loc    = (const float*)d_in[0];
    const float* conf   = (const float*)d_in[1];
    const float* priors = (const float*)d_in[2];
    const float* gt     = (const float*)d_in[3];
    const int*   labels = (const int*)d_in[4];
    float* out = (float*)d_out;
    int*      wi = (int*)d_ws;
    float*    wf = (float*)d_ws;
    unsigned* wu = (unsigned*)d_ws;
    unsigned long long* wbp = (unsigned long long*)(wi + W_BP);

    hipMemsetAsync(d_ws, 0, MEMSET_BYTES, stream);  // counters + bp + hists
    k_best_prior<<<dim3(NOBJ, BB, BPSPLIT), 256, 0, stream>>>(priors, gt, wbp);
    k_match<<<dim3((PP + 255) / 256, BB), 256, 0, stream>>>(
        loc, priors, gt, labels, wbp, wi + W_CONF, wf, wi);
    k_conf<<<ROWS / RPB, 256, 0, stream>>>(conf, wi + W_CONF, wu + W_KEY,
                                           wf + W_CE, wf);
    k_sel<<<SELBLK, 256, 0, stream>>>(wu + W_KEY, wi, wu + W_HA, wu + W_HB,
                                      wu + W_HC);
    k_negsum<<<NEGBLK, 256, 0, stream>>>(wu + W_KEY, wf + W_CE, wi + W_CONF,
                                         wi, wf, out);
}

// Round 6
// 507.367 us; speedup vs baseline: 1.7745x; 1.6050x over previous
//
#include <hip/hip_runtime.h>
#include <math.h>

#define BB 8
#define PP 57744
#define NOBJ 20
#define CC 81
#define ROWS (BB*PP)
#define RPB 64        // rows per block in k_conf (round-0 proven structure)
#define BPSPLIT 16
#define BPCHUNK ((PP + BPSPLIT - 1) / BPSPLIT)   // 3609
#define SELBLK 1024   // k_sel blocks — co-resident (4-wave, ~9KB-LDS: cap >=2048)

// ws layout in 4-byte units
// cnt: [0]=num_pos [1]=sl1_sum(f) [2]=pos_ce(f) [3]=neg_ce(f) [4]=neg_cnt
//      [5]=eqCtr [6]=doneA [7]=skip [8]=prefixA [9]=KrB [10]=T [11]=eqSlots
//      [12]=doneB [13]=doneD [14]=flagB [15]=prefixAB [16]=KrC [17]=doneC
//      [20]=flagA [21]=flagD
#define W_CNT  0
#define W_BP   64                      // 160 u64 (byte 256, 8-aligned)
#define W_HA   1024                    // 8 copies x 2048 bins
#define W_HB   (W_HA + 8*2048)
#define W_HC   (W_HB + 8*2048)         // 8 copies x 1024
#define W_CONF (W_HC + 8*1024)         // ROWS ints
#define W_KEY  (W_CONF + ROWS)
#define W_CE   (W_KEY + ROWS)
#define MEMSET_BYTES (W_CONF * 4)      // counters + bp + hists

#define SCOPE_AGENT __HIP_MEMORY_SCOPE_AGENT
// Completion (not fence) ordering: all prior vmem ops (incl. non-returning
// atomics) retired at the coherence point before anything after this line.
// Deliberately NOT __threadfence(): no buffer_wbl2 / buffer_inv emitted.
#define VMEM_DRAIN() asm volatile("s_waitcnt vmcnt(0) lgkmcnt(0)" ::: "memory")

__device__ __forceinline__ unsigned keymap(float f) {
    unsigned u = __float_as_uint(f);
    return (u & 0x80000000u) ? ~u : (u | 0x80000000u);
}

__device__ __forceinline__ float smooth_l1(float d) {
    float a = fabsf(d);
    return a < 1.f ? 0.5f * d * d : a - 0.5f;
}

__device__ __forceinline__ unsigned aload_u(const unsigned* p) {
    return __hip_atomic_load(p, __ATOMIC_RELAXED, SCOPE_AGENT);
}
__device__ __forceinline__ int aload_i(const int* p) {
    return __hip_atomic_load(p, __ATOMIC_RELAXED, SCOPE_AGENT);
}
__device__ __forceinline__ float aload_f(const float* p) {
    return __hip_atomic_load(p, __ATOMIC_RELAXED, SCOPE_AGENT);
}
__device__ __forceinline__ void astore_i(int* p, int v) {
    __hip_atomic_store(p, v, __ATOMIC_RELAXED, SCOPE_AGENT);
}

// Descending-cumulative threshold search over NB bins summed across NC global
// copies (relaxed agent loads -> coherence-point values). Finds bin B with
// suffix(B) >= Kr && suffix(B+1) < Kr; *rem_out = Kr - suffix(B+1).
// Returns -1 if total < Kr. One block, 256 threads.
template <int NB, int NC>
__device__ int scan_bins(const unsigned* h, unsigned Kr, unsigned* rem_out) {
    constexpr int BPT = NB / 256;
    __shared__ unsigned stot[256];
    __shared__ int sbin;
    __shared__ unsigned srem;
    int i = threadIdx.x;
    unsigned v[BPT];
    unsigned tot = 0;
    #pragma unroll
    for (int j = 0; j < BPT; j++) {
        unsigned s = 0;
        #pragma unroll
        for (int c = 0; c < NC; c++) s += aload_u(h + c * NB + i * BPT + j);
        v[j] = s; tot += s;
    }
    if (i == 0) sbin = -1;
    stot[i] = tot; __syncthreads();
    for (int off = 1; off < 256; off <<= 1) {   // inclusive suffix scan
        unsigned add = (i + off < 256) ? stot[i + off] : 0u;
        __syncthreads(); stot[i] += add; __syncthreads();
    }
    unsigned cum = (i < 255) ? stot[i + 1] : 0u;   // suffix of threads > i
    #pragma unroll
    for (int j = BPT - 1; j >= 0; j--) {
        unsigned nxt = cum;      // suffix(bin+1)
        cum += v[j];             // suffix(bin)
        if (cum >= Kr && nxt < Kr) { sbin = i * BPT + j; srem = Kr - nxt; }
    }
    __syncthreads();
    *rem_out = (sbin >= 0) ? srem : 0u;
    return sbin;
}

// Grid (NOBJ, BB, BPSPLIT): per-(gt,batch) argmax over a prior chunk.
__global__ void k_best_prior(const float* __restrict__ priors,
                             const float* __restrict__ gt,
                             unsigned long long* __restrict__ bp) {
    int n = blockIdx.x, b = blockIdx.y;
    int p0 = blockIdx.z * BPCHUNK;
    int p1 = min(p0 + BPCHUNK, PP);
    const float* t = gt + (b * NOBJ + n) * 4;
    float tx1 = t[0], ty1 = t[1], tx2 = t[2], ty2 = t[3];
    float ta = (tx2 - tx1) * (ty2 - ty1);
    unsigned long long best = 0ull;
    for (int p = p0 + threadIdx.x; p < p1; p += 256) {
        float4 pr = ((const float4*)priors)[p];
        float px1 = pr.x - pr.z * 0.5f, py1 = pr.y - pr.w * 0.5f;
        float px2 = pr.x + pr.z * 0.5f, py2 = pr.y + pr.w * 0.5f;
        float iw = fmaxf(fminf(tx2, px2) - fmaxf(tx1, px1), 0.f);
        float ih = fmaxf(fminf(ty2, py2) - fmaxf(ty1, py1), 0.f);
        float inter = iw * ih;
        float iou = inter / (ta + (px2 - px1) * (py2 - py1) - inter);
        unsigned long long pk = ((unsigned long long)__float_as_uint(iou) << 32)
                              | (unsigned long long)(0xFFFFFFFFu - (unsigned)p);
        if (pk > best) best = pk;
    }
    __shared__ unsigned long long sb[256];
    int tid = threadIdx.x;
    sb[tid] = best; __syncthreads();
    for (int s = 128; s > 0; s >>= 1) {
        if (tid < s && sb[tid + s] > sb[tid]) sb[tid] = sb[tid + s];
        __syncthreads();
    }
    if (tid == 0) atomicMax(&bp[b * NOBJ + n], sb[0]);
}

// Per prior: best truth, force-match, conf_t, smooth-L1 for positives.
__global__ void k_match(const float* __restrict__ loc_data,
                        const float* __restrict__ priors,
                        const float* __restrict__ gt,
                        const int* __restrict__ labels,
                        const unsigned long long* __restrict__ bp,
                        int* __restrict__ conf_t,
                        float* __restrict__ cnt_f,
                        int* __restrict__ cnt_i) {
    int b = blockIdx.y;
    int tid = threadIdx.x;
    int p = blockIdx.x * 256 + tid;
    __shared__ float st[NOBJ][4];
    __shared__ int slab[NOBJ], sbp[NOBJ];
    if (tid < NOBJ * 4) ((float*)st)[tid] = gt[b * NOBJ * 4 + tid];
    if (tid < NOBJ) {
        slab[tid] = labels[b * NOBJ + tid];
        sbp[tid] = (int)(0xFFFFFFFFu - (unsigned)bp[b * NOBJ + tid]);
    }
    __syncthreads();
    float s_l1 = 0.f; int is_pos = 0;
    if (p < PP) {
        float4 pr = ((const float4*)priors)[p];
        float px1 = pr.x - pr.z * 0.5f, py1 = pr.y - pr.w * 0.5f;
        float px2 = pr.x + pr.z * 0.5f, py2 = pr.y + pr.w * 0.5f;
        float pa = (px2 - px1) * (py2 - py1);
        float best = -1.f; int bn = 0;
        for (int n = 0; n < NOBJ; n++) {
            float tx1 = st[n][0], ty1 = st[n][1], tx2 = st[n][2], ty2 = st[n][3];
            float iw = fmaxf(fminf(tx2, px2) - fmaxf(tx1, px1), 0.f);
            float ih = fmaxf(fminf(ty2, py2) - fmaxf(ty1, py1), 0.f);
            float inter = iw * ih;
            float iou = inter / ((tx2 - tx1) * (ty2 - ty1) + pa - inter);
            if (iou > best) { best = iou; bn = n; }
        }
        float ov = best;
        for (int n = 0; n < NOBJ; n++)
            if (sbp[n] == p) { bn = n; ov = 2.0f; }
        int conf = slab[bn];
        if (ov < 0.5f) conf = -1;
        if (ov < 0.4f) conf = 0;
        conf_t[b * PP + p] = conf;
        if (conf > 0) {
            is_pos = 1;
            float mx1 = st[bn][0], my1 = st[bn][1], mx2 = st[bn][2], my2 = st[bn][3];
            float gcx = ((mx1 + mx2) * 0.5f - pr.x) / (0.1f * pr.z);
            float gcy = ((my1 + my2) * 0.5f - pr.y) / (0.1f * pr.w);
            float gw = logf((mx2 - mx1) / pr.z) / 0.2f;
            float gh = logf((my2 - my1) / pr.w) / 0.2f;
            float4 ld = ((const float4*)loc_data)[b * PP + p];
            s_l1 = smooth_l1(ld.x - gcx) + smooth_l1(ld.y - gcy) +
                   smooth_l1(ld.z - gw) + smooth_l1(ld.w - gh);
        }
    }
    __shared__ float rs[256]; __shared__ int rc[256];
    rs[tid] = s_l1; rc[tid] = is_pos; __syncthreads();
    for (int s = 128; s > 0; s >>= 1) {
        if (tid < s) { rs[tid] += rs[tid + s]; rc[tid] += rc[tid + s]; }
        __syncthreads();
    }
    if (tid == 0) {
        if (rs[0] != 0.f) atomicAdd(&cnt_f[1], rs[0]);
        if (rc[0])        atomicAdd(&cnt_i[0], rc[0]);
    }
}

// Round-0 proven structure: 64 rows per one-shot block staged via coalesced
// float4 -> LDS; 4 threads/row serial scan with native exp2/log2.
// 7218 blocks * 5184 floats == ROWS*81 exactly.
__global__ void __launch_bounds__(256) k_conf(const float* __restrict__ conf_data,
                                              const int* __restrict__ conf_t,
                                              unsigned* __restrict__ key,
                                              float* __restrict__ ce,
                                              float* __restrict__ cnt_f) {
    __shared__ float sx[RPB * CC];   // 20736 B
    int tid = threadIdx.x;
    const float4* g = (const float4*)(conf_data + (size_t)blockIdx.x * (RPB * CC));
    float4* s4 = (float4*)sx;
    #pragma unroll
    for (int i = 0; i < 5; i++) s4[tid + 256 * i] = g[tid + 256 * i];
    if (tid < (RPB * CC / 4) - 1280) s4[1280 + tid] = g[1280 + tid];
    __syncthreads();

    int r = tid >> 2, t = tid & 3;
    int row = blockIdx.x * RPB + r;
    const float* x = sx + r * CC;

    float m = (t == 0) ? x[0] : -INFINITY;
    float fg = -INFINITY;
    for (int c = (t == 0) ? 4 : t; c < CC; c += 4) {
        float v = x[c];
        m = fmaxf(m, v);
        fg = fmaxf(fg, v);
    }
    m = fmaxf(m, __shfl_xor(m, 1));
    m = fmaxf(m, __shfl_xor(m, 2));
    fg = fmaxf(fg, __shfl_xor(fg, 1));
    fg = fmaxf(fg, __shfl_xor(fg, 2));

    const float LOG2E = 1.4426950408889634f;
    float e = 0.f;
    for (int c = t; c < CC; c += 4) e += exp2f((x[c] - m) * LOG2E);
    e += __shfl_xor(e, 1);
    e += __shfl_xor(e, 2);

    if (t == 0) {
        float lse = m + log2f(e) * 0.6931471805599453f;
        int ct = conf_t[row];
        int ctc = min(max(ct, 0), CC - 1);
        float cev = lse - x[ctc];
        ce[row] = cev;
        key[row] = (ct == 0) ? keymap(fg) : 0u;
        if (ct > 0) atomicAdd(&cnt_f[2], cev);
    }
}

// All three radix-select phases (bits 31:21, 20:10, 9:0) PLUS the negative-CE
// sum and final loss computation, in ONE kernel. Cross-block sync uses ONLY
// relaxed agent-scope atomics (coherence-point ops, no buffer_wbl2/buffer_inv
// cache maintenance — the round-5 410us lesson) with writer-side ordering by
// s_waitcnt vmcnt(0) completion and reader-side ordering by data dependence.
// SELBLK=1024 blocks are co-resident (4-wave/9KB-LDS -> capacity >=2048), so
// the spins cannot deadlock.
__global__ void __launch_bounds__(256) k_sel(const unsigned* __restrict__ key,
                                             const float* __restrict__ ce,
                                             const int* __restrict__ conf_t,
                                             int* __restrict__ cnt_i,
                                             float* __restrict__ cnt_f,
                                             unsigned* __restrict__ hA,
                                             unsigned* __restrict__ hB,
                                             unsigned* __restrict__ hC,
                                             float* __restrict__ out) {
    __shared__ unsigned lh[2048];
    __shared__ int amLast;
    int tid = threadIdx.x;
    const uint4* k4 = (const uint4*)key;
    int n4 = ROWS / 4;

    // ---- phase A: bits 31:21 ----
    for (int j = tid; j < 2048; j += 256) lh[j] = 0;
    __syncthreads();
    for (int r = blockIdx.x * 256 + tid; r < n4; r += gridDim.x * 256) {
        uint4 k = k4[r];
        if (k.x) atomicAdd(&lh[k.x >> 21], 1u);
        if (k.y) atomicAdd(&lh[k.y >> 21], 1u);
        if (k.z) atomicAdd(&lh[k.z >> 21], 1u);
        if (k.w) atomicAdd(&lh[k.w >> 21], 1u);
    }
    __syncthreads();
    {
        unsigned* hmy = hA + (blockIdx.x & 7) * 2048;
        for (int j = tid; j < 2048; j += 256)
            if (lh[j]) atomicAdd(&hmy[j], lh[j]);
    }
    VMEM_DRAIN();   // my hist adds are at the coherence point
    if (tid == 0)
        amLast = (__hip_atomic_fetch_add((unsigned*)&cnt_i[6], 1u,
                   __ATOMIC_RELAXED, SCOPE_AGENT) == (unsigned)(gridDim.x - 1));
    __syncthreads();
    if (amLast) {
        unsigned Kr = 3u * (unsigned)aload_i(&cnt_i[0]);
        if (Kr == 0) {           // no positives: select no negatives
            if (tid == 0) {
                astore_i(&cnt_i[10], (int)0xFFFFFFFFu); astore_i(&cnt_i[11], 0);
                astore_i(&cnt_i[7], 1);
                VMEM_DRAIN();
                astore_i(&cnt_i[20], 1);  // flagA
                astore_i(&cnt_i[21], 1);  // flagD (B/C skipped)
            }
        } else {
            unsigned rem; int bin = scan_bins<2048, 8>(hA, Kr, &rem);
            if (tid == 0) {
                if (bin < 0) {   // total < Kr: select all candidates
                    astore_i(&cnt_i[10], 0); astore_i(&cnt_i[11], 0);
                    astore_i(&cnt_i[7], 1);
                    VMEM_DRAIN();
                    astore_i(&cnt_i[20], 1);
                    astore_i(&cnt_i[21], 1);
                } else {
                    astore_i(&cnt_i[8], bin);
                    astore_i(&cnt_i[9], (int)rem);
                    VMEM_DRAIN();
                    astore_i(&cnt_i[20], 1);
                }
            }
        }
    }
    if (tid == 0) {   // relaxed spin: no cache-invalidate per iteration
        while (aload_i(&cnt_i[20]) == 0) __builtin_amdgcn_s_sleep(2);
    }
    __syncthreads();
    int skip = aload_i(&cnt_i[7]);

    if (!skip) {
        unsigned prefixA = (unsigned)aload_i(&cnt_i[8]);
        unsigned KrB = (unsigned)aload_i(&cnt_i[9]);

        // ---- phase B: bits 20:10 within prefixA ----
        for (int j = tid; j < 2048; j += 256) lh[j] = 0;
        __syncthreads();
        for (int r = blockIdx.x * 256 + tid; r < n4; r += gridDim.x * 256) {
            uint4 k = k4[r];
            if (k.x && (k.x >> 21) == prefixA) atomicAdd(&lh[(k.x >> 10) & 0x7FFu], 1u);
            if (k.y && (k.y >> 21) == prefixA) atomicAdd(&lh[(k.y >> 10) & 0x7FFu], 1u);
            if (k.z && (k.z >> 21) == prefixA) atomicAdd(&lh[(k.z >> 10) & 0x7FFu], 1u);
            if (k.w && (k.w >> 21) == prefixA) atomicAdd(&lh[(k.w >> 10) & 0x7FFu], 1u);
        }
        __syncthreads();
        {
            unsigned* hmy = hB + (blockIdx.x & 7) * 2048;
            for (int j = tid; j < 2048; j += 256)
                if (lh[j]) atomicAdd(&hmy[j], lh[j]);
        }
        VMEM_DRAIN();
        if (tid == 0)
            amLast = (__hip_atomic_fetch_add((unsigned*)&cnt_i[12], 1u,
                       __ATOMIC_RELAXED, SCOPE_AGENT) == (unsigned)(gridDim.x - 1));
        __syncthreads();
        if (amLast) {
            unsigned rem; int bin = scan_bins<2048, 8>(hB, KrB, &rem);
            if (bin < 0) { bin = 0; rem = 0; }   // defensive (cannot happen)
            if (tid == 0) {
                astore_i(&cnt_i[15], (int)((prefixA << 11) | (unsigned)bin));
                astore_i(&cnt_i[16], (int)rem);
                VMEM_DRAIN();
                astore_i(&cnt_i[14], 1);  // flagB
            }
        }
        if (tid == 0) {
            while (aload_i(&cnt_i[14]) == 0) __builtin_amdgcn_s_sleep(2);
        }
        __syncthreads();
        unsigned prefixAB = (unsigned)aload_i(&cnt_i[15]);
        unsigned KrC = (unsigned)aload_i(&cnt_i[16]);

        // ---- phase C: bits 9:0 within prefixAB ----
        for (int j = tid; j < 1024; j += 256) lh[j] = 0;
        __syncthreads();
        for (int r = blockIdx.x * 256 + tid; r < n4; r += gridDim.x * 256) {
            uint4 k = k4[r];
            if (k.x && (k.x >> 10) == prefixAB) atomicAdd(&lh[k.x & 0x3FFu], 1u);
            if (k.y && (k.y >> 10) == prefixAB) atomicAdd(&lh[k.y & 0x3FFu], 1u);
            if (k.z && (k.z >> 10) == prefixAB) atomicAdd(&lh[k.z & 0x3FFu], 1u);
            if (k.w && (k.w >> 10) == prefixAB) atomicAdd(&lh[k.w & 0x3FFu], 1u);
        }
        __syncthreads();
        {
            unsigned* hmy = hC + (blockIdx.x & 7) * 1024;
            for (int j = tid; j < 1024; j += 256)
                if (lh[j]) atomicAdd(&hmy[j], lh[j]);
        }
        VMEM_DRAIN();
        if (tid == 0)
            amLast = (__hip_atomic_fetch_add((unsigned*)&cnt_i[17], 1u,
                       __ATOMIC_RELAXED, SCOPE_AGENT) == (unsigned)(gridDim.x - 1));
        __syncthreads();
        if (amLast) {
            unsigned rem; int bin = scan_bins<1024, 8>(hC, KrC, &rem);
            if (bin < 0) { bin = 0; rem = 0; }   // defensive
            if (tid == 0) {
                astore_i(&cnt_i[10], (int)((prefixAB << 10) | (unsigned)bin));
                astore_i(&cnt_i[11], (int)rem);
                VMEM_DRAIN();
                astore_i(&cnt_i[21], 1);  // flagD
            }
        }
    }

    // ---- phase D: sum CE over selected negatives + final losses ----
    if (tid == 0) {
        while (aload_i(&cnt_i[21]) == 0) __builtin_amdgcn_s_sleep(2);
    }
    __syncthreads();
    unsigned T = (unsigned)aload_i(&cnt_i[10]);
    int eqS = aload_i(&cnt_i[11]);
    float s = 0.f; int c = 0;
    const int4* ct4 = (const int4*)conf_t;
    for (int r = blockIdx.x * 256 + tid; r < n4; r += gridDim.x * 256) {
        uint4 k = k4[r]; int4 ctv = ct4[r];
        #define DO_ONE(comp, idx) { \
            if (ctv.comp == 0) { \
                unsigned kk = k.comp; bool selr = false; \
                if (kk > T) selr = true; \
                else if (kk == T) { int slot = atomicAdd(&cnt_i[5], 1); selr = slot < eqS; } \
                if (selr) { s += ce[4 * r + idx]; c++; } \
            } }
        DO_ONE(x, 0) DO_ONE(y, 1) DO_ONE(z, 2) DO_ONE(w, 3)
        #undef DO_ONE
    }
    __shared__ float rs[256]; __shared__ int rc[256];
    rs[tid] = s; rc[tid] = c; __syncthreads();
    for (int st = 128; st > 0; st >>= 1) {
        if (tid < st) { rs[tid] += rs[tid + st]; rc[tid] += rc[tid + st]; }
        __syncthreads();
    }
    if (tid == 0) {
        if (rs[0] != 0.f) atomicAdd(&cnt_f[3], rs[0]);
        if (rc[0])        atomicAdd(&cnt_i[4], rc[0]);
    }
    VMEM_DRAIN();   // my partial sums are at the coherence point
    if (tid == 0 &&
        __hip_atomic_fetch_add((unsigned*)&cnt_i[13], 1u,
            __ATOMIC_RELAXED, SCOPE_AGENT) == (unsigned)(gridDim.x - 1)) {
        int np = aload_i(&cnt_i[0]);
        int nn = aload_i(&cnt_i[4]);
        float f1 = aload_f(&cnt_f[1]);
        float f2 = aload_f(&cnt_f[2]);
        float f3 = aload_f(&cnt_f[3]);
        out[0] = f1 / (float)max(np, 1);
        out[1] = (f2 + f3) / (float)max(np + nn, 1);
    }
}

extern "C" void kernel_launch(void* const* d_in, const int* in_sizes, int n_in,
                              void* d_out, int out_size, void* d_ws, size_t ws_size,
                              hipStream_t stream) {
    const float* loc    = (const float*)d_in[0];
    const float* conf   = (const float*)d_in[1];
    const float* priors = (const float*)d_in[2];
    const float* gt     = (const float*)d_in[3];
    const int*   labels = (const int*)d_in[4];
    float* out = (float*)d_out;
    int*      wi = (int*)d_ws;
    float*    wf = (float*)d_ws;
    unsigned* wu = (unsigned*)d_ws;
    unsigned long long* wbp = (unsigned long long*)(wi + W_BP);

    hipMemsetAsync(d_ws, 0, MEMSET_BYTES, stream);  // counters + bp + hists
    k_best_prior<<<dim3(NOBJ, BB, BPSPLIT), 256, 0, stream>>>(priors, gt, wbp);
    k_match<<<dim3((PP + 255) / 256, BB), 256, 0, stream>>>(
        loc, priors, gt, labels, wbp, wi + W_CONF, wf, wi);
    k_conf<<<ROWS / RPB, 256, 0, stream>>>(conf, wi + W_CONF, wu + W_KEY,
                                           wf + W_CE, wf);
    k_sel<<<SELBLK, 256, 0, stream>>>(wu + W_KEY, wf + W_CE, wi + W_CONF,
                                      wi, wf, wu + W_HA, wu + W_HB, wu + W_HC,
                                      out);
}